// Round 4
// baseline (1479.517 us; speedup 1.0000x reference)
//
#include <hip/hip_runtime.h>

// V=5000, C=128, K=64. One fused persistent kernel (16 blocks x 256).
// Solve op'(W^) = RH, op'(W) = E W H + LMB[W Q0 - Dr1 W Qr - Di1 W Qi],
// E = Mx^T(A A^T)Mx + LMB diag(r1r^2+r1i^2), H = My^T My.
// Congruence by Le=chol(E), Lh=chol(H): At(Y) = Y + LMB[E0 Y Qt0 - Er Y Qtr - Ei Y Qti].
#define NV 5000
#define LMB 100.0f
#define MAXIT 150
#define TOL 1e-10f
#define NBLK 16

// ---- workspace float offsets ----
#define SV_O     0
#define PART_O   256
#define A_O      131328
#define B0_O     139520
#define BC_O     147712
#define H_O      155904
#define G_O      160000
#define T1_O     164096
#define Z1_O     168192
#define E_O      172288
#define RH2_O    176384
#define RH_O     180480
#define Q0_O     184576
#define QR_O     188672
#define QI_O     192768
#define LIH_O    196864
#define LIE_O    200960
#define U0_O     205056
#define UR_O     209152
#define UI_O     213248
#define QT0_O    217344
#define QTR_O    221440
#define QTI_O    225536
#define E0_O     229632
#define ER_O     233728
#define EI_O     237824
#define TB_O     241920
#define BT_O     246016
#define RSTK_O   250112
#define LCT_O    266496
#define RG_O     282880
#define XG_O     286976
#define V1_O     291072
#define WH_O     295168
#define CT_O     299264   // cnt int [0..15], RZ at +16 (160), PQ at +176 (160)
#define WS_NEED  299776

__device__ __forceinline__ float aload(const float* p) {
  return __hip_atomic_load(p, __ATOMIC_RELAXED, __HIP_MEMORY_SCOPE_AGENT);
}
__device__ __forceinline__ void astore(float* p, float v) {
  __hip_atomic_store(p, v, __ATOMIC_RELAXED, __HIP_MEMORY_SCOPE_AGENT);
}

__global__ void init_kernel(float* ctrl) {
  for (int e = threadIdx.x; e < 512; e += 256) ctrl[e] = 0.f;
}

__device__ __forceinline__ void gbar(int* cnt, int target) {
  __syncthreads();
  if (threadIdx.x == 0) {
    __hip_atomic_fetch_add(cnt, 1, __ATOMIC_ACQ_REL, __HIP_MEMORY_SCOPE_AGENT);
    while (__hip_atomic_load(cnt, __ATOMIC_ACQUIRE, __HIP_MEMORY_SCOPE_AGENT) < target) {
      __builtin_amdgcn_s_sleep(2);
    }
  }
  __syncthreads();
}

__device__ __forceinline__ void red_atomic(float v, float* red, float* dst) {
  int tid = threadIdx.x;
  red[tid] = v;
  __syncthreads();
  if (tid < 128) red[tid] += red[tid + 128];
  __syncthreads();
  if (tid < 64) {
    float s = red[tid] + red[tid + 64];
#pragma unroll
    for (int o = 32; o > 0; o >>= 1) s += __shfl_down(s, o, 64);
    if (tid == 0) atomicAdd(dst, s);
  }
  __syncthreads();
}

// ---- small-GEMM job helpers (full 64x64 output by one 256-thread block) ----
__device__ void mmTN(const float* L, const float* R, float* D) {  // D[i][j]=sum_t L[t][i]R[t][j]
  int tid = threadIdx.x;
  for (int e = tid; e < 4096; e += 256) {
    int i = e >> 6, j = e & 63;
    float acc = 0.f;
    for (int t = 0; t < 64; ++t) acc = fmaf(aload(L + t * 64 + i), aload(R + t * 64 + j), acc);
    astore(D + e, acc);
  }
}
__device__ void mmNN(const float* L, const float* R, float* D) {  // D[i][j]=sum_t L[i][t]R[t][j]
  int tid = threadIdx.x;
  for (int e = tid; e < 4096; e += 256) {
    int i = e >> 6, j = e & 63;
    float acc = 0.f;
    for (int t = 0; t < 64; ++t) acc = fmaf(aload(L + i * 64 + t), aload(R + t * 64 + j), acc);
    astore(D + e, acc);
  }
}
__device__ void mmNT(const float* L, const float* R, float* D) {  // D[i][j]=sum_t L[i][t]R[j][t]
  int tid = threadIdx.x;
  for (int e = tid; e < 4096; e += 256) {
    int i = e >> 6, j = e & 63;
    float acc = 0.f;
    for (int t = 0; t < 64; ++t) acc = fmaf(aload(L + i * 64 + t), aload(R + j * 64 + t), acc);
    astore(D + e, acc);
  }
}

// ---- 64x64 SPD Cholesky + explicit L^-1 (row-major lower, zero upper) ----
__device__ void chol_inv(const float* S, float* Li, float* sm) {
  float (*M)[65] = (float (*)[65])sm;
  float (*T)[65] = (float (*)[65])(sm + 64 * 65);
  int tid = threadIdx.x;
  for (int e = tid; e < 4096; e += 256) {
    M[e >> 6][e & 63] = aload(S + e);
    T[e >> 6][e & 63] = 0.f;
  }
  __syncthreads();
  for (int j = 0; j < 64; ++j) {
    float pv = M[j][j];
    __syncthreads();
    float sc = rsqrtf(pv);
    if (tid < 64 - j) M[j + tid][j] *= sc;
    __syncthreads();
    int m = 63 - j, c2 = (m * (m + 1)) >> 1;
    for (int e = tid; e < c2; e += 256) {
      int rp = (int)((sqrtf(8.f * (float)e + 1.f) - 1.f) * 0.5f);
      while (((rp + 1) * (rp + 2)) >> 1 <= e) ++rp;
      while ((rp * (rp + 1)) >> 1 > e) --rp;
      int cp = e - ((rp * (rp + 1)) >> 1);
      int r = j + 1 + rp, c = j + 1 + cp;
      M[r][c] = fmaf(-M[r][j], M[c][j], M[r][c]);
    }
    __syncthreads();
  }
  if (tid < 64) {
    int c = tid;
    T[c][c] = 1.f / M[c][c];
    for (int r = c + 1; r < 64; ++r) {
      float s = 0.f;
      for (int t = c; t < r; ++t) s = fmaf(M[r][t], T[t][c], s);
      T[r][c] = -s / M[r][r];
    }
  }
  __syncthreads();
  for (int e = tid; e < 4096; e += 256) astore(Li + e, T[e >> 6][e & 63]);
}

// ---- partial projection: Opart[64][128] = P[:, v0:v0+625] @ f[v0:v0+625, :] ----
__device__ void proj_seg(const float* P, const float* f, float* Opart, float* sm) {
  float* Pl = sm;  // [64][126]
  int tid = threadIdx.x;
  int rg = (tid >> 5) << 3;   // 0,8,..,56
  int cq = (tid & 31) << 2;   // 0,4,..,124
  float acc[8][4];
#pragma unroll
  for (int u = 0; u < 8; ++u)
#pragma unroll
    for (int v = 0; v < 4; ++v) acc[u][v] = 0.f;
  for (int t5 = 0; t5 < 5; ++t5) {
    int vb = t5 * 125;
    __syncthreads();
    for (int e = tid; e < 8000; e += 256) {
      int rr = e / 125, vv = e - rr * 125;
      Pl[rr * 126 + vv] = P[rr * NV + vb + vv];
    }
    __syncthreads();
    for (int vv = 0; vv < 125; ++vv) {
      float4 fv = *(const float4*)(f + (vb + vv) * 128 + cq);
#pragma unroll
      for (int u = 0; u < 8; ++u) {
        float pv = Pl[(rg + u) * 126 + vv];
        acc[u][0] = fmaf(pv, fv.x, acc[u][0]);
        acc[u][1] = fmaf(pv, fv.y, acc[u][1]);
        acc[u][2] = fmaf(pv, fv.z, acc[u][2]);
        acc[u][3] = fmaf(pv, fv.w, acc[u][3]);
      }
    }
  }
#pragma unroll
  for (int u = 0; u < 8; ++u)
#pragma unroll
    for (int v = 0; v < 4; ++v) astore(Opart + (rg + u) * 128 + cq + v, acc[u][v]);
}

__global__ __launch_bounds__(256) void fused_kernel(
    const float* fx, const float* fy, const float* ex, const float* ey,
    const float* Px, const float* Py, const float* Mx, const float* My,
    float* W, float* out) {
  __shared__ float smem[8500];
  __shared__ float red[256];
  __shared__ float scal[4];
  int tid = threadIdx.x, blk = blockIdx.x;
  int lane = tid & 63, wv = tid >> 6;
  int* cnt = (int*)(W + CT_O);
  float* RZ = W + CT_O + 16;
  float* PQ = W + CT_O + 176;
  int bt = 0;

  // ---- P0: sv (blk 0) + projection partials (all blocks) ----
  if (blk == 0 && tid < 64) {
    float vx = ex[tid], vy = ey[tid];
    float m = fmaxf(vx, vy);
#pragma unroll
    for (int o = 32; o > 0; o >>= 1) m = fmaxf(m, __shfl_xor(m, o, 64));
    float g1 = sqrtf(vx / m), g2 = sqrtf(vy / m);   // GAMMA = 0.5
    float d1 = 1.f / fmaf(g1, g1, 1.f), d2 = 1.f / fmaf(g2, g2, 1.f);
    astore(W + SV_O + tid, g1 * d1);
    astore(W + SV_O + 64 + tid, d1);
    astore(W + SV_O + 128 + tid, g2 * d2);
    astore(W + SV_O + 192 + tid, d2);
  }
  {
    int mat = blk & 1, seg = blk >> 1;
    const float* P = mat ? Py : Px;
    const float* f = mat ? fy : fx;
    proj_seg(P + seg * 625, f + seg * 625 * 128, W + PART_O + blk * 8192, smem);
  }
  gbar(cnt, (++bt) * NBLK);

  // ---- P1: reduce A (blk 0-3), B0 (4-7), H (8-15) ----
  if (blk < 4) {
    int base = blk * 2048;
    for (int u = 0; u < 8; ++u) {
      int e = base + u * 256 + tid;
      float s = 0.f;
      for (int p = 0; p < 8; ++p) s += aload(W + PART_O + (2 * p) * 8192 + e);
      astore(W + A_O + e, s);
    }
  } else if (blk < 8) {
    int base = (blk - 4) * 2048;
    for (int u = 0; u < 8; ++u) {
      int e = base + u * 256 + tid;
      float s = 0.f;
      for (int p = 0; p < 8; ++p) s += aload(W + PART_O + (2 * p + 1) * 8192 + e);
      astore(W + B0_O + e, s);
    }
  } else {
    int base = (blk - 8) * 512;
    for (int u = 0; u < 2; ++u) {
      int e = base + u * 256 + tid;
      int i = e >> 6, j = e & 63;
      float acc = 0.f;
      for (int t = 0; t < 64; ++t) acc = fmaf(My[t * 64 + i], My[t * 64 + j], acc);
      astore(W + H_O + e, acc);
    }
  }
  gbar(cnt, (++bt) * NBLK);

  // ---- P2: G (0-1), Bc (2-3), Q0/Qr/Qi (4-6), chol(H) (7) ----
  if (blk < 2) {
    int base = blk * 2048;
    for (int u = 0; u < 8; ++u) {
      int e = base + u * 256 + tid;
      int i = e >> 6, j = e & 63;
      float acc = 0.f;
      for (int c = 0; c < 128; ++c) acc = fmaf(aload(W + A_O + i * 128 + c), aload(W + A_O + j * 128 + c), acc);
      astore(W + G_O + e, acc);
    }
  } else if (blk < 4) {
    int base = (blk - 2) * 4096;
    for (int u = 0; u < 16; ++u) {
      int e = base + u * 256 + tid;
      int i = e >> 7, c = e & 127;
      float acc = 0.f;
      for (int j = 0; j < 64; ++j) acc = fmaf(My[i * 64 + j], aload(W + B0_O + j * 128 + c), acc);
      astore(W + BC_O + e, acc);
    }
  } else if (blk == 4) {
    for (int e = tid; e < 4096; e += 256) {
      int k = e >> 6, b = e & 63;
      float h = aload(W + H_O + e);
      astore(W + Q0_O + e, h * (aload(W + SV_O + 128 + k) * aload(W + SV_O + 128 + b) +
                                aload(W + SV_O + 192 + k) * aload(W + SV_O + 192 + b)));
    }
  } else if (blk == 5) {
    for (int e = tid; e < 4096; e += 256) {
      int k = e >> 6, b = e & 63;
      astore(W + QR_O + e, aload(W + H_O + e) * (aload(W + SV_O + 128 + k) + aload(W + SV_O + 128 + b)));
    }
  } else if (blk == 6) {
    for (int e = tid; e < 4096; e += 256) {
      int k = e >> 6, b = e & 63;
      astore(W + QI_O + e, aload(W + H_O + e) * (aload(W + SV_O + 192 + k) + aload(W + SV_O + 192 + b)));
    }
  } else if (blk == 7) {
    chol_inv(W + H_O, W + LIH_O, smem);
  }
  gbar(cnt, (++bt) * NBLK);

  // ---- P3: T1=Mx^T G (0), Z1=A Bc^T (1), U*=Lih Q* (2-4) ----
  if (blk == 0) mmTN(Mx, W + G_O, W + T1_O);
  else if (blk == 1) {
    for (int e = tid; e < 4096; e += 256) {
      int i = e >> 6, j = e & 63;
      float acc = 0.f;
      for (int c = 0; c < 128; ++c) acc = fmaf(aload(W + A_O + i * 128 + c), aload(W + BC_O + j * 128 + c), acc);
      astore(W + Z1_O + e, acc);
    }
  } else if (blk == 2) mmNN(W + LIH_O, W + Q0_O, W + U0_O);
  else if (blk == 3) mmNN(W + LIH_O, W + QR_O, W + UR_O);
  else if (blk == 4) mmNN(W + LIH_O, W + QI_O, W + UI_O);
  gbar(cnt, (++bt) * NBLK);

  // ---- P4: E = T1 Mx + LMB diag (0), RH2=Mx^T Z1 (1), QT*=U* Lih^T (2-4) ----
  if (blk == 0) {
    for (int e = tid; e < 4096; e += 256) {
      int i = e >> 6, j = e & 63;
      float acc = 0.f;
      for (int t = 0; t < 64; ++t) acc = fmaf(aload(W + T1_O + i * 64 + t), Mx[t * 64 + j], acc);
      if (i == j) {
        float a = aload(W + SV_O + i), b = aload(W + SV_O + 64 + i);
        acc += LMB * (a * a + b * b);
      }
      astore(W + E_O + e, acc);
    }
  } else if (blk == 1) mmTN(Mx, W + Z1_O, W + RH2_O);
  else if (blk == 2) mmNT(W + U0_O, W + LIH_O, W + QT0_O);
  else if (blk == 3) mmNT(W + UR_O, W + LIH_O, W + QTR_O);
  else if (blk == 4) mmNT(W + UI_O, W + LIH_O, W + QTI_O);
  gbar(cnt, (++bt) * NBLK);

  // ---- P5: chol(E) (0), RH=RH2 My (1), RSTK pack (2-5), LCT t0 (6) ----
  if (blk == 0) chol_inv(W + E_O, W + LIE_O, smem);
  else if (blk == 1) mmNN(W + RH2_O, My, W + RH_O);
  else if (blk >= 2 && blk <= 5) {
    int t = blk - 2;
    const float* Q = (t == 1) ? W + QT0_O : (t == 2) ? W + QTR_O : W + QTI_O;
    for (int e = tid; e < 4096; e += 256) {
      int a = e >> 6, b = e & 63;
      float rv = (t == 0) ? ((a == b) ? 1.f : 0.f)
                          : 0.5f * (aload(Q + a * 64 + b) + aload(Q + b * 64 + a));
      astore(W + RSTK_O + t * 4096 + e, rv);
    }
  } else if (blk == 6) {
    for (int e = tid; e < 4096; e += 256) {
      int k = e >> 6, i = e & 63;
      astore(W + LCT_O + e, (k == i) ? 1.f : 0.f);
    }
  }
  gbar(cnt, (++bt) * NBLK);

  // ---- P6: E0 (0), Er (1), Ei (2), TB=Lie RH (3) ----
  if (blk == 0) mmNT(W + LIE_O, W + LIE_O, W + E0_O);
  else if (blk == 1) {
    for (int e = tid; e < 4096; e += 256) {
      int i = e >> 6, j = e & 63;
      float acc = 0.f;
      for (int k = 0; k < 64; ++k)
        acc = fmaf(aload(W + LIE_O + i * 64 + k) * aload(W + SV_O + k), aload(W + LIE_O + j * 64 + k), acc);
      astore(W + ER_O + e, acc);
    }
  } else if (blk == 2) {
    for (int e = tid; e < 4096; e += 256) {
      int i = e >> 6, j = e & 63;
      float acc = 0.f;
      for (int k = 0; k < 64; ++k)
        acc = fmaf(aload(W + LIE_O + i * 64 + k) * aload(W + SV_O + 64 + k), aload(W + LIE_O + j * 64 + k), acc);
      astore(W + EI_O + e, acc);
    }
  } else if (blk == 3) mmNN(W + LIE_O, W + RH_O, W + TB_O);
  gbar(cnt, (++bt) * NBLK);

  // ---- P7: BT = TB Lih^T (0), LCT t1-t3 (1-3) ----
  if (blk == 0) mmNT(W + TB_O, W + LIH_O, W + BT_O);
  else if (blk >= 1 && blk <= 3) {
    int t = blk;
    const float* Emat = (t == 1) ? W + E0_O : (t == 2) ? W + ER_O : W + EI_O;
    float sgn = (t == 1) ? LMB : -LMB;
    for (int e = tid; e < 4096; e += 256) {
      int k = e >> 6, i = e & 63;
      float lv = sgn * 0.5f * (aload(Emat + k * 64 + i) + aload(Emat + i * 64 + k));
      astore(W + LCT_O + t * 4096 + e, lv);
    }
  }
  gbar(cnt, (++bt) * NBLK);

  // ---- P8: CG on At(Y)=BT (16 blocks, 4 cols each) ----
  {
    float (*pT)[68] = (float (*)[68])smem;            // pT[col][row], 64x68
    float* Rown = smem + 64 * 68;                     // [4][4][64]
    float* Tt = smem + 64 * 68 + 1024;                // [4][256]
    const float* BT = W + BT_O;
    const float* RSTK = W + RSTK_O;
    const float* LCT = W + LCT_O;
    float* rg = W + RG_O;
    float* xg = W + XG_O;
    int j0 = blk * 4;
    int jown = j0 + wv;
    for (int e = tid; e < 1024; e += 256) {
      int t = e >> 8, jl = (e >> 6) & 3, m = e & 63;
      Rown[t * 256 + jl * 64 + m] = aload(RSTK + (t * 64 + j0 + jl) * 64 + m);
    }
    if (blk == 0) {
      for (int u = 0; u < 16; ++u) {
        int g = u * 256 + tid;  // g = j*64+i (col-major dest)
        astore(&rg[g], aload(BT + (g & 63) * 64 + (g >> 6)));
      }
    }
    {
      float v = aload(BT + lane * 64 + jown);
      red_atomic(v * v, red, &RZ[0]);
    }
    gbar(cnt, (++bt) * NBLK);
    float x_reg = 0.f;
    float rl = aload(BT + lane * 64 + jown);
    for (int it = 0; it < MAXIT; ++it) {
      if (tid == 0) {
        scal[0] = aload(&RZ[it]);
        scal[1] = (it == 0) ? 1.f : aload(&RZ[it - 1]);
        scal[2] = aload(&RZ[0]);
      }
      __syncthreads();
      float rrold = scal[0];
      if (it > 0 && rrold < TOL * scal[2]) break;
      float beta = (it == 0) ? 0.f : rrold / scal[1];
      for (int u = 0; u < 16; ++u) {
        int g = u * 256 + tid;  // col-major: j=g>>6, i=g&63
        float rv = aload(&rg[g]);
        pT[g >> 6][g & 63] = (it == 0) ? rv : fmaf(beta, pT[g >> 6][g & 63], rv);
      }
      __syncthreads();
      // stage1: Tt[jl][t*64+k] = sum_m p[k][m] * Rstk_t[j0+jl][m]  (t=wv, k=lane)
      {
        float a0 = 0.f, a1 = 0.f, a2 = 0.f, a3 = 0.f;
        const float* R0 = Rown + wv * 256;
        for (int m = 0; m < 64; ++m) {
          float pv = pT[m][lane];
          a0 = fmaf(pv, R0[m], a0);
          a1 = fmaf(pv, R0[64 + m], a1);
          a2 = fmaf(pv, R0[128 + m], a2);
          a3 = fmaf(pv, R0[192 + m], a3);
        }
        Tt[0 * 256 + wv * 64 + lane] = a0;
        Tt[1 * 256 + wv * 64 + lane] = a1;
        Tt[2 * 256 + wv * 64 + lane] = a2;
        Tt[3 * 256 + wv * 64 + lane] = a3;
      }
      __syncthreads();
      // stage2: q[i=lane][jown] = sum_tk LCT[tk][i] * Tt[wv][tk]
      float q_reg;
      {
        const float* Lc = LCT + lane;
        const float* Tw = Tt + wv * 256;
        float a0 = 0.f, a1 = 0.f, a2 = 0.f, a3 = 0.f;
        for (int tk = 0; tk < 256; tk += 4) {
          a0 = fmaf(aload(Lc + (tk + 0) * 64), Tw[tk + 0], a0);
          a1 = fmaf(aload(Lc + (tk + 1) * 64), Tw[tk + 1], a1);
          a2 = fmaf(aload(Lc + (tk + 2) * 64), Tw[tk + 2], a2);
          a3 = fmaf(aload(Lc + (tk + 3) * 64), Tw[tk + 3], a3);
        }
        q_reg = (a0 + a1) + (a2 + a3);
      }
      float pv_own = pT[jown][lane];
      red_atomic(pv_own * q_reg, red, &PQ[it]);
      gbar(cnt, (++bt) * NBLK);
      if (tid == 0) scal[3] = aload(&PQ[it]);
      __syncthreads();
      float alpha = rrold / scal[3];
      x_reg = fmaf(alpha, pv_own, x_reg);
      rl = fmaf(-alpha, q_reg, rl);
      astore(&rg[jown * 64 + lane], rl);
      red_atomic(rl * rl, red, &RZ[it + 1]);
      gbar(cnt, (++bt) * NBLK);
    }
    astore(&xg[jown * 64 + lane], x_reg);  // Y col-major: xg[j*64+i]
  }
  gbar(cnt, (++bt) * NBLK);

  // ---- P9: V1 = Lie^T Y : V1[t][b] = sum_a Lie[a][t] Y[a][b] ----
  {
    int e = blk * 256 + tid;
    int t = e >> 6, b = e & 63;
    float acc = 0.f;
    for (int a = 0; a < 64; ++a)
      acc = fmaf(aload(W + LIE_O + a * 64 + t), aload(W + XG_O + b * 64 + a), acc);
    astore(W + V1_O + e, acc);
  }
  gbar(cnt, (++bt) * NBLK);

  // ---- P10: WH = V1 Lih : WH[t][c] = sum_b V1[t][b] Lih[b][c] ----
  {
    int e = blk * 256 + tid;
    int t = e >> 6, c = e & 63;
    float acc = 0.f;
    for (int b = 0; b < 64; ++b)
      acc = fmaf(aload(W + V1_O + t * 64 + b), aload(W + LIH_O + b * 64 + c), acc);
    astore(W + WH_O + e, acc);
  }
  gbar(cnt, (++bt) * NBLK);

  // ---- P11: out[r][c] = sum_t Mx[c][t] WH[t][r] ----
  {
    int e = blk * 256 + tid;
    int r = e >> 6, c = e & 63;
    float acc = 0.f;
    for (int t = 0; t < 64; ++t)
      acc = fmaf(Mx[c * 64 + t], aload(W + WH_O + t * 64 + r), acc);
    out[e] = acc;
  }
}

extern "C" void kernel_launch(void* const* d_in, const int* in_sizes, int n_in,
                              void* d_out, int out_size, void* d_ws, size_t ws_size,
                              hipStream_t stream) {
  const float* fx = (const float*)d_in[0];
  const float* fy = (const float*)d_in[1];
  const float* ex = (const float*)d_in[2];
  const float* ey = (const float*)d_in[3];
  const float* Px = (const float*)d_in[4];
  const float* Py = (const float*)d_in[5];
  const float* Mx = (const float*)d_in[6];
  const float* My = (const float*)d_in[7];
  float* out = (float*)d_out;
  float* W = (float*)d_ws;

  if (ws_size < (size_t)WS_NEED * sizeof(float)) {
    hipMemsetAsync(d_out, 0, (size_t)out_size * sizeof(float), stream);
    return;
  }

  init_kernel<<<1, 256, 0, stream>>>(W + CT_O);
  fused_kernel<<<NBLK, 256, 0, stream>>>(fx, fy, ex, ey, Px, Py, Mx, My, W, out);
}

// Round 5
// 693.433 us; speedup vs baseline: 2.1336x; 2.1336x over previous
//
#include <hip/hip_runtime.h>

// V=5000, C=128, K=64. Mx-congruence basis + chol(E)/chol(H) congruence, pipelined CG.
// op'(W) = E W H + LMB[W Q0 - Dr1 W Qr - Di1 W Qi];  E = Ahat Ahat^T + LMB diag(r1r^2+r1i^2)
// Ahat = Mx^T A; H = My^T My; rhs = Ahat B0^T H.
// Congruence: At(Y) = Y + LMB[E0 Y Qt0 - Er Y Qtr - Ei Y Qti], solve At(Y)=BT by pipelined CG.
#define NV 5000
#define LMB 100.0f
#define MAXIT 150
#define TOL 1e-10f
#define NBLK 16

// ---- workspace float offsets ----
#define SV_O    0
#define AH_O    256
#define A_O     8448
#define B0_O    16640
#define H_O     24832
#define E_O     28928
#define Z2_O    33024
#define RH_O    37120
#define Q0_O    41216
#define QR_O    45312
#define QI_O    49408
#define LIH_O   53504
#define LIE_O   57600
#define U0_O    61696
#define UR_O    65792
#define UI_O    69888
#define QT0_O   73984
#define QTR_O   78080
#define QTI_O   82176
#define E0_O    86272
#define ER_O    90368
#define EI_O    94464
#define TB_O    98560
#define BT_O    102656
#define RSTK_O  106752
#define LCT_O   123136
#define WG_O    139520
#define XG_O    143616
#define CT_O    147712   // cnt ints [0..15]; RZ floats at +16 (160); PQ at +176 (160)
#define WS_NEED 148224

__device__ __forceinline__ float aload(const float* p) {
  return __hip_atomic_load(p, __ATOMIC_RELAXED, __HIP_MEMORY_SCOPE_AGENT);
}
__device__ __forceinline__ void astore(float* p, float v) {
  __hip_atomic_store(p, v, __ATOMIC_RELAXED, __HIP_MEMORY_SCOPE_AGENT);
}

// ---- zero A,B0 (16384) + ctrl (512) ----
__global__ void zero_kernel(float* W) {
  int e = blockIdx.x * 256 + threadIdx.x;
  if (e < 16384) W[A_O + e] = 0.f;
  else if (e < 16896) W[CT_O + (e - 16384)] = 0.f;
}

// ---- A += Px fx, B0 += Py fy (split-K atomics); blk 80: scalar vectors ----
__global__ __launch_bounds__(256) void proj_kernel(const float* Px, const float* fx,
                                                   const float* Py, const float* fy,
                                                   const float* ex, const float* ey, float* W) {
  int b = blockIdx.x, tid = threadIdx.x;
  if (b == 80) {
    if (tid < 64) {
      float vx = ex[tid], vy = ey[tid];
      float m = fmaxf(vx, vy);
#pragma unroll
      for (int o = 32; o > 0; o >>= 1) m = fmaxf(m, __shfl_xor(m, o, 64));
      float g1 = sqrtf(vx / m), g2 = sqrtf(vy / m);   // GAMMA = 0.5
      float d1 = 1.f / fmaf(g1, g1, 1.f), d2 = 1.f / fmaf(g2, g2, 1.f);
      W[SV_O + tid] = g1 * d1;          // r1r
      W[SV_O + 64 + tid] = d1;          // r1i
      W[SV_O + 128 + tid] = g2 * d2;    // d2r
      W[SV_O + 192 + tid] = d2;         // d2i
    }
    return;
  }
  int mat = b & 1, chunk = b >> 1;
  const float* P = mat ? Py : Px;
  const float* f = mat ? fy : fx;
  float* O = W + (mat ? B0_O : A_O);
  int v0 = chunk * 125;
  __shared__ float Pl[125 * 65];
  int lane = tid & 63, wv = tid >> 6;
  for (int ii = wv; ii < 64; ii += 4)
    for (int vv = lane; vv < 125; vv += 64)
      Pl[vv * 65 + ii] = P[ii * NV + v0 + vv];
  __syncthreads();
  int c = tid & 127, half = tid >> 7;
  float acc[32];
#pragma unroll
  for (int u = 0; u < 32; ++u) acc[u] = 0.f;
  for (int v = 0; v < 125; ++v) {
    float fv = f[(v0 + v) * 128 + c];
    const float* pl = Pl + v * 65 + half * 32;
#pragma unroll
    for (int u = 0; u < 32; ++u) acc[u] = fmaf(pl[u], fv, acc[u]);
  }
  for (int u = 0; u < 32; ++u) atomicAdd(&O[(half * 32 + u) * 128 + c], acc[u]);
}

// ---- small GEMM helpers (plain memory, one block per full 64x64 output) ----
__device__ void mmNN(const float* L, const float* R, float* D) {  // D=L*R
  int tid = threadIdx.x;
  for (int e = tid; e < 4096; e += 256) {
    int i = e >> 6, j = e & 63;
    float acc = 0.f;
    for (int t = 0; t < 64; ++t) acc = fmaf(L[i * 64 + t], R[t * 64 + j], acc);
    D[e] = acc;
  }
}
__device__ void mmNT(const float* L, const float* R, float* D) {  // D=L*R^T
  int tid = threadIdx.x;
  for (int e = tid; e < 4096; e += 256) {
    int i = e >> 6, j = e & 63;
    float acc = 0.f;
    for (int t = 0; t < 64; ++t) acc = fmaf(L[i * 64 + t], R[j * 64 + t], acc);
    D[e] = acc;
  }
}

// ---- 64x64 SPD Cholesky + explicit L^-1 (lower, zero upper) ----
__device__ void chol_inv(const float* S, float* Li, float* sm) {
  float (*M)[65] = (float (*)[65])sm;
  float (*T)[65] = (float (*)[65])(sm + 64 * 65);
  int tid = threadIdx.x;
  for (int e = tid; e < 4096; e += 256) {
    M[e >> 6][e & 63] = S[e];
    T[e >> 6][e & 63] = 0.f;
  }
  __syncthreads();
  for (int j = 0; j < 64; ++j) {
    float pv = M[j][j];
    __syncthreads();
    float sc = rsqrtf(pv);
    if (tid < 64 - j) M[j + tid][j] *= sc;
    __syncthreads();
    int m = 63 - j, c2 = (m * (m + 1)) >> 1;
    for (int e = tid; e < c2; e += 256) {
      int rp = (int)((sqrtf(8.f * (float)e + 1.f) - 1.f) * 0.5f);
      while (((rp + 1) * (rp + 2)) >> 1 <= e) ++rp;
      while ((rp * (rp + 1)) >> 1 > e) --rp;
      int cp = e - ((rp * (rp + 1)) >> 1);
      int r = j + 1 + rp, c = j + 1 + cp;
      M[r][c] = fmaf(-M[r][j], M[c][j], M[r][c]);
    }
    __syncthreads();
  }
  if (tid < 64) {
    int c = tid;
    T[c][c] = 1.f / M[c][c];
    for (int r = c + 1; r < 64; ++r) {
      float s = 0.f;
      for (int t = c; t < r; ++t) s = fmaf(M[r][t], T[t][c], s);
      T[r][c] = -s / M[r][r];
    }
  }
  __syncthreads();
  for (int e = tid; e < 4096; e += 256) Li[e] = T[e >> 6][e & 63];
}

// ---- prepA: Ahat = Mx^T A (blk 0-7) | H = My^T My (blk 8-15) ----
__global__ __launch_bounds__(256) void prepA_kernel(const float* Mx, const float* My, float* W) {
  int blk = blockIdx.x, tid = threadIdx.x;
  const float* A = W + A_O;
  if (blk < 8) {
    for (int u = 0; u < 4; ++u) {
      int e = blk * 1024 + u * 256 + tid;
      int i = e >> 7, c = e & 127;
      float acc = 0.f;
      for (int t = 0; t < 64; ++t) acc = fmaf(Mx[t * 64 + i], A[t * 128 + c], acc);
      W[AH_O + e] = acc;
    }
  } else {
    for (int u = 0; u < 2; ++u) {
      int e = (blk - 8) * 512 + u * 256 + tid;
      int i = e >> 6, j = e & 63;
      float acc = 0.f;
      for (int t = 0; t < 64; ++t) acc = fmaf(My[t * 64 + i], My[t * 64 + j], acc);
      W[H_O + e] = acc;
    }
  }
}

// ---- prepB: E (0-3), Z2=Ahat B0^T (4-7), Q0/Qr/Qi (8-10), chol(H) (11) ----
__global__ __launch_bounds__(256) void prepB_kernel(float* W) {
  __shared__ float sm[2 * 64 * 65];
  int blk = blockIdx.x, tid = threadIdx.x;
  const float* Ah = W + AH_O;
  const float* sv = W + SV_O;
  const float* H = W + H_O;
  if (blk < 4) {
    for (int u = 0; u < 4; ++u) {
      int e = blk * 1024 + u * 256 + tid;
      int i = e >> 6, j = e & 63;
      float acc = 0.f;
      for (int c = 0; c < 128; ++c) acc = fmaf(Ah[i * 128 + c], Ah[j * 128 + c], acc);
      if (i == j) { float a = sv[i], b2 = sv[64 + i]; acc += LMB * (a * a + b2 * b2); }
      W[E_O + e] = acc;
    }
  } else if (blk < 8) {
    const float* B0 = W + B0_O;
    for (int u = 0; u < 4; ++u) {
      int e = (blk - 4) * 1024 + u * 256 + tid;
      int i = e >> 6, j = e & 63;
      float acc = 0.f;
      for (int c = 0; c < 128; ++c) acc = fmaf(Ah[i * 128 + c], B0[j * 128 + c], acc);
      W[Z2_O + e] = acc;
    }
  } else if (blk == 8) {
    for (int e = tid; e < 4096; e += 256) {
      int k = e >> 6, b = e & 63;
      W[Q0_O + e] = H[e] * (sv[128 + k] * sv[128 + b] + sv[192 + k] * sv[192 + b]);
    }
  } else if (blk == 9) {
    for (int e = tid; e < 4096; e += 256) {
      int k = e >> 6, b = e & 63;
      W[QR_O + e] = H[e] * (sv[128 + k] + sv[128 + b]);
    }
  } else if (blk == 10) {
    for (int e = tid; e < 4096; e += 256) {
      int k = e >> 6, b = e & 63;
      W[QI_O + e] = H[e] * (sv[192 + k] + sv[192 + b]);
    }
  } else {
    chol_inv(H, W + LIH_O, sm);
  }
}

// ---- prepC: chol(E) (0), RH=Z2 H (1), U*=LiH Q* (2-4) ----
__global__ __launch_bounds__(256) void prepC_kernel(float* W) {
  __shared__ float sm[2 * 64 * 65];
  int blk = blockIdx.x;
  if (blk == 0) chol_inv(W + E_O, W + LIE_O, sm);
  else if (blk == 1) mmNN(W + Z2_O, W + H_O, W + RH_O);
  else if (blk == 2) mmNN(W + LIH_O, W + Q0_O, W + U0_O);
  else if (blk == 3) mmNN(W + LIH_O, W + QR_O, W + UR_O);
  else mmNN(W + LIH_O, W + QI_O, W + UI_O);
}

// ---- prepD: TB=LiE RH (0), QT*=U* LiH^T (1-3), E0/Er/Ei (4-6) ----
__global__ __launch_bounds__(256) void prepD_kernel(float* W) {
  int blk = blockIdx.x, tid = threadIdx.x;
  const float* LiE = W + LIE_O;
  const float* sv = W + SV_O;
  if (blk == 0) mmNN(LiE, W + RH_O, W + TB_O);
  else if (blk == 1) mmNT(W + U0_O, W + LIH_O, W + QT0_O);
  else if (blk == 2) mmNT(W + UR_O, W + LIH_O, W + QTR_O);
  else if (blk == 3) mmNT(W + UI_O, W + LIH_O, W + QTI_O);
  else if (blk == 4) mmNT(LiE, LiE, W + E0_O);
  else {
    const float* d = (blk == 5) ? sv : sv + 64;   // r1r or r1i
    float* D = W + ((blk == 5) ? ER_O : EI_O);
    for (int e = tid; e < 4096; e += 256) {
      int i = e >> 6, j = e & 63;
      float acc = 0.f;
      for (int k = 0; k < 64; ++k) acc = fmaf(LiE[i * 64 + k] * d[k], LiE[j * 64 + k], acc);
      D[e] = acc;
    }
  }
}

// ---- prepE: BT=TB LiH^T (0), RSTK pack (1), LCT pack (2) ----
__global__ __launch_bounds__(256) void prepE_kernel(float* W) {
  int blk = blockIdx.x, tid = threadIdx.x;
  if (blk == 0) mmNT(W + TB_O, W + LIH_O, W + BT_O);
  else if (blk == 1) {
    for (int e = tid; e < 16384; e += 256) {
      int t = e >> 12, a = (e >> 6) & 63, b = e & 63;
      float rv;
      if (t == 0) rv = (a == b) ? 1.f : 0.f;
      else {
        const float* Q = W + ((t == 1) ? QT0_O : (t == 2) ? QTR_O : QTI_O);
        rv = 0.5f * (Q[a * 64 + b] + Q[b * 64 + a]);
      }
      W[RSTK_O + e] = rv;
    }
  } else {
    for (int e = tid; e < 16384; e += 256) {
      int t = e >> 12, k = (e >> 6) & 63, i = e & 63;
      float lv;
      if (t == 0) lv = (k == i) ? 1.f : 0.f;
      else {
        const float* Emat = W + ((t == 1) ? E0_O : (t == 2) ? ER_O : EI_O);
        float sgn = (t == 1) ? LMB : -LMB;
        lv = sgn * 0.5f * (Emat[k * 64 + i] + Emat[i * 64 + k]);
      }
      W[LCT_O + e] = lv;
    }
  }
}

__device__ __forceinline__ void gbar(int* cnt, int target) {
  __syncthreads();
  if (threadIdx.x == 0) {
    __hip_atomic_fetch_add(cnt, 1, __ATOMIC_ACQ_REL, __HIP_MEMORY_SCOPE_AGENT);
    while (__hip_atomic_load(cnt, __ATOMIC_ACQUIRE, __HIP_MEMORY_SCOPE_AGENT) < target) {
      __builtin_amdgcn_s_sleep(2);
    }
  }
  __syncthreads();
}

__device__ __forceinline__ void red_atomic(float v, float* red, float* dst) {
  int tid = threadIdx.x;
  red[tid] = v;
  __syncthreads();
  if (tid < 128) red[tid] += red[tid + 128];
  __syncthreads();
  if (tid < 64) {
    float s = red[tid] + red[tid + 64];
#pragma unroll
    for (int o = 32; o > 0; o >>= 1) s += __shfl_down(s, o, 64);
    if (tid == 0) atomicAdd(dst, s);
  }
  __syncthreads();
}

// apply At to matrix in pT (pT[col][row]); returns own element (row=lane, col=j0+wv)
__device__ __forceinline__ float at_apply(const float (*pT)[68], const float* Rown, float* Tt,
                                          const float* LCT, int lane, int wv) {
  float a0 = 0.f, a1 = 0.f, a2 = 0.f, a3 = 0.f;
  const float* R0 = Rown + wv * 256;     // t = wv
  for (int m = 0; m < 64; ++m) {
    float pv = pT[m][lane];              // p[row=lane][col=m]
    a0 = fmaf(pv, R0[m], a0);
    a1 = fmaf(pv, R0[64 + m], a1);
    a2 = fmaf(pv, R0[128 + m], a2);
    a3 = fmaf(pv, R0[192 + m], a3);
  }
  Tt[0 + wv * 64 + lane] = a0;           // [jl][t][k] with t=wv, k=lane
  Tt[256 + wv * 64 + lane] = a1;
  Tt[512 + wv * 64 + lane] = a2;
  Tt[768 + wv * 64 + lane] = a3;
  __syncthreads();
  const float* Lc = LCT + lane;
  const float* Tw = Tt + wv * 256;       // jl = wv
  float b0 = 0.f, b1 = 0.f, b2 = 0.f, b3 = 0.f;
  for (int tk = 0; tk < 256; tk += 4) {
    b0 = fmaf(Lc[(tk + 0) * 64], Tw[tk + 0], b0);
    b1 = fmaf(Lc[(tk + 1) * 64], Tw[tk + 1], b1);
    b2 = fmaf(Lc[(tk + 2) * 64], Tw[tk + 2], b2);
    b3 = fmaf(Lc[(tk + 3) * 64], Tw[tk + 3], b3);
  }
  return (b0 + b1) + (b2 + b3);
}

// ---- pipelined CG (Ghysels-Vanroose): ONE barrier + ONE apply per iteration ----
__global__ __launch_bounds__(256) void cg_kernel(float* W) {
  __shared__ float pT[64][68];
  __shared__ float Rown[1024];
  __shared__ float Tt[1024];
  __shared__ float red[256];
  __shared__ float scal[3];
  int tid = threadIdx.x, blk = blockIdx.x;
  int lane = tid & 63, wv = tid >> 6;
  int j0 = blk * 4, jown = j0 + wv;
  const float* BT = W + BT_O;
  const float* RSTK = W + RSTK_O;
  const float* LCT = W + LCT_O;
  float* wg = W + WG_O;
  int* cnt = (int*)(W + CT_O);
  float* RZ = W + CT_O + 16;
  float* PQ = W + CT_O + 176;

  for (int e = tid; e < 1024; e += 256) {
    int t = e >> 8, jl = (e >> 6) & 3, m = e & 63;
    Rown[t * 256 + jl * 64 + m] = RSTK[(t * 64 + j0 + jl) * 64 + m];
  }
  // r0 = b; w0 = At(r0)
  for (int u = 0; u < 16; ++u) {
    int g = u * 256 + tid;               // g = col*64+row
    pT[g >> 6][g & 63] = BT[(g & 63) * 64 + (g >> 6)];
  }
  __syncthreads();
  float w_l = at_apply(pT, Rown, Tt, LCT, lane, wv);
  float r_l = BT[lane * 64 + jown];
  astore(&wg[jown * 64 + lane], w_l);
  red_atomic(r_l * r_l, red, &RZ[0]);
  red_atomic(w_l * r_l, red, &PQ[0]);
  int bt = 0;
  gbar(cnt, (++bt) * NBLK);

  float p_l = 0.f, q_l = 0.f, z_l = 0.f, x_l = 0.f;
  float gprev = 1.f, aprev = 1.f;
  for (int j = 0; j < MAXIT; ++j) {
    if (tid == 0) {
      scal[0] = aload(&RZ[j]);
      scal[1] = aload(&PQ[j]);
      scal[2] = aload(&RZ[0]);
    }
    __syncthreads();
    float gj = scal[0], dj = scal[1], g0 = scal[2];
    if (j > 0 && gj < TOL * g0) break;
    float bj = (j == 0) ? 0.f : gj / gprev;
    float aj = (j == 0) ? gj / dj : gj / (dj - bj * gj / aprev);
    // n = At(w_j): load global w into pT
    for (int u = 0; u < 16; ++u) {
      int g = u * 256 + tid;
      pT[g >> 6][g & 63] = aload(&wg[g]);
    }
    __syncthreads();
    float n_l = at_apply(pT, Rown, Tt, LCT, lane, wv);
    z_l = fmaf(bj, z_l, n_l);
    q_l = fmaf(bj, q_l, w_l);
    p_l = fmaf(bj, p_l, r_l);
    x_l = fmaf(aj, p_l, x_l);
    r_l = fmaf(-aj, q_l, r_l);
    w_l = fmaf(-aj, z_l, w_l);
    astore(&wg[jown * 64 + lane], w_l);
    red_atomic(r_l * r_l, red, &RZ[j + 1]);
    red_atomic(w_l * r_l, red, &PQ[j + 1]);
    gprev = gj; aprev = aj;
    gbar(cnt, (++bt) * NBLK);
  }
  astore(&W[XG_O + jown * 64 + lane], x_l);   // Y col-major
}

// ---- finish: out[r][c] = sum_t Mx[c][t] (LiE^T Y LiH)[t][r] ----
__global__ __launch_bounds__(256) void finish_kernel(const float* Mx, float* W, float* out) {
  __shared__ float Ys[64 * 65];
  __shared__ float V1[64 * 65];
  __shared__ float WH[64 * 65];
  int tid = threadIdx.x;
  const float* xg = W + XG_O;     // xg[j*64+i] = Y[i][j]
  const float* LiE = W + LIE_O;
  const float* LiH = W + LIH_O;
  for (int e = tid; e < 4096; e += 256) Ys[(e >> 6) * 65 + (e & 63)] = xg[e];  // Ys[j][i] = Y[i][j]
  __syncthreads();
  for (int e = tid; e < 4096; e += 256) {   // V1[t][b] = sum_a LiE[a][t] Y[a][b]
    int t = e >> 6, b = e & 63;
    float acc = 0.f;
    for (int a = 0; a < 64; ++a) acc = fmaf(LiE[a * 64 + t], Ys[b * 65 + a], acc);
    V1[t * 65 + b] = acc;
  }
  __syncthreads();
  for (int e = tid; e < 4096; e += 256) {   // WH[t][c] = sum_b V1[t][b] LiH[b][c]
    int t = e >> 6, c = e & 63;
    float acc = 0.f;
    for (int b = 0; b < 64; ++b) acc = fmaf(V1[t * 65 + b], LiH[b * 64 + c], acc);
    WH[t * 65 + c] = acc;
  }
  __syncthreads();
  for (int e = tid; e < 4096; e += 256) {   // out[r][c] = sum_t Mx[c][t] WH[t][r]
    int r = e >> 6, c = e & 63;
    float acc = 0.f;
    for (int t = 0; t < 64; ++t) acc = fmaf(Mx[c * 64 + t], WH[t * 65 + r], acc);
    out[e] = acc;
  }
}

extern "C" void kernel_launch(void* const* d_in, const int* in_sizes, int n_in,
                              void* d_out, int out_size, void* d_ws, size_t ws_size,
                              hipStream_t stream) {
  const float* fx = (const float*)d_in[0];
  const float* fy = (const float*)d_in[1];
  const float* ex = (const float*)d_in[2];
  const float* ey = (const float*)d_in[3];
  const float* Px = (const float*)d_in[4];
  const float* Py = (const float*)d_in[5];
  const float* Mx = (const float*)d_in[6];
  const float* My = (const float*)d_in[7];
  float* out = (float*)d_out;
  float* W = (float*)d_ws;

  if (ws_size < (size_t)WS_NEED * sizeof(float)) {
    hipMemsetAsync(d_out, 0, (size_t)out_size * sizeof(float), stream);
    return;
  }

  zero_kernel<<<66, 256, 0, stream>>>(W);
  proj_kernel<<<81, 256, 0, stream>>>(Px, fx, Py, fy, ex, ey, W);
  prepA_kernel<<<16, 256, 0, stream>>>(Mx, My, W);
  prepB_kernel<<<12, 256, 0, stream>>>(W);
  prepC_kernel<<<5, 256, 0, stream>>>(W);
  prepD_kernel<<<7, 256, 0, stream>>>(W);
  prepE_kernel<<<3, 256, 0, stream>>>(W);
  cg_kernel<<<NBLK, 256, 0, stream>>>(W);
  finish_kernel<<<1, 256, 0, stream>>>(Mx, W, out);
}

// Round 6
// 638.644 us; speedup vs baseline: 2.3167x; 1.0858x over previous
//
#include <hip/hip_runtime.h>

// V=5000, C=128, K=64. Fully fused persistent kernel (16 blocks x 256) + ctrl-init.
// Math (R5-proven): solve op'(Wh)=RH in Mx-congruence basis via chol(E)/chol(H)
// congruence + pipelined CG on At(Y) = Y + LMB[E0 Y Qt0 - Er Y Qtr - Ei Y Qti].
// Data-movement rule: cross-block data via relaxed agent atomics, ALWAYS batch-staged
// into LDS/regs (R4 post-mortem: aload inside FMA loops serializes at L2 latency).
#define NV 5000
#define LMB 100.0f
#define MAXIT 150
#define TOL 1e-10f
#define NBLK 16

// ---- workspace float offsets ----
#define SV_O    0
#define PART_O  256
#define AH_O    131328
#define B0_O    139520
#define H_O     147712
#define E_O     151808
#define Z2_O    155904
#define RH_O    160000
#define Q0_O    164096
#define QR_O    168192
#define QI_O    172288
#define LIH_O   176384
#define LIE_O   180480
#define U0_O    184576
#define UR_O    188672
#define UI_O    192768
#define QT0_O   196864
#define QTR_O   200960
#define QTI_O   205056
#define E0_O    209152
#define ER_O    213248
#define EI_O    217344
#define TB_O    221440
#define BT_O    225536
#define RSTK_O  229632
#define LCT_O   246016
#define WG_O    262400
#define XG_O    266496
#define CTRL_O  270592
#define RZP_O   271616
#define PQP_O   274048
#define WS_NEED 276544

__device__ __forceinline__ float aload(const float* p) {
  return __hip_atomic_load(p, __ATOMIC_RELAXED, __HIP_MEMORY_SCOPE_AGENT);
}
__device__ __forceinline__ void astore(float* p, float v) {
  __hip_atomic_store(p, v, __ATOMIC_RELAXED, __HIP_MEMORY_SCOPE_AGENT);
}

__global__ void init_kernel(int* ctrl) {
  ctrl[blockIdx.x * 256 + threadIdx.x] = 0;   // 1024 ints
}

// flag-tree barrier: per-block flag lines (128B apart) + go word. No RMW contention.
__device__ __forceinline__ void gbar2(int* ctrl, int blk, int bt) {
  __syncthreads();
  int tid = threadIdx.x;
  if (blk == 0) {
    if (tid > 0 && tid < NBLK) {
      while (__hip_atomic_load(&ctrl[tid * 32], __ATOMIC_ACQUIRE, __HIP_MEMORY_SCOPE_AGENT) < bt)
        __builtin_amdgcn_s_sleep(1);
    }
    __syncthreads();
    if (tid == 0)
      __hip_atomic_store(&ctrl[NBLK * 32], bt, __ATOMIC_RELEASE, __HIP_MEMORY_SCOPE_AGENT);
  } else {
    if (tid == 0) {
      __hip_atomic_store(&ctrl[blk * 32], bt, __ATOMIC_RELEASE, __HIP_MEMORY_SCOPE_AGENT);
      while (__hip_atomic_load(&ctrl[NBLK * 32], __ATOMIC_ACQUIRE, __HIP_MEMORY_SCOPE_AGENT) < bt)
        __builtin_amdgcn_s_sleep(1);
    }
  }
  __syncthreads();
}

// two simultaneous block reductions -> out2[0], out2[1]
__device__ __forceinline__ void red2(float v1, float v2, float* red, float* out2) {
  int tid = threadIdx.x;
  red[tid] = v1;
  red[256 + tid] = v2;
  __syncthreads();
  if (tid < 128) {
    red[tid] += red[tid + 128];
    red[256 + tid] += red[384 + tid];
  }
  __syncthreads();
  if (tid < 64) {
    float s1 = red[tid] + red[tid + 64];
    float s2 = red[256 + tid] + red[320 + tid];
#pragma unroll
    for (int o = 32; o > 0; o >>= 1) {
      s1 += __shfl_down(s1, o, 64);
      s2 += __shfl_down(s2, o, 64);
    }
    if (tid == 0) { out2[0] = s1; out2[1] = s2; }
  }
  __syncthreads();
}

// ---- LDS staging + 64x64 GEMM helpers (aloads only in batched staging loops) ----
__device__ __forceinline__ void stageN(float* dst, const float* src) {   // padded row-major
  for (int e = threadIdx.x; e < 4096; e += 256)
    dst[(e >> 6) * 65 + (e & 63)] = aload(src + e);
}
__device__ __forceinline__ void stageT(float* dst, const float* src) {   // padded transpose
  for (int e = threadIdx.x; e < 4096; e += 256)
    dst[(e & 63) * 65 + (e >> 6)] = aload(src + e);
}
__device__ __forceinline__ void mm65(const float* Ls, const float* Rs, float* D) {
  for (int e = threadIdx.x; e < 4096; e += 256) {
    int i = e >> 6, j = e & 63;
    float acc = 0.f;
#pragma unroll 8
    for (int t = 0; t < 64; ++t) acc = fmaf(Ls[i * 65 + t], Rs[t * 65 + j], acc);
    astore(D + e, acc);
  }
}
__device__ void mmNN_s(const float* L, const float* R, float* D, float* sm) {
  stageN(sm, L); stageN(sm + 4160, R);
  __syncthreads();
  mm65(sm, sm + 4160, D);
}
__device__ void mmNT_s(const float* L, const float* R, float* D, float* sm) {
  stageN(sm, L); stageT(sm + 4160, R);
  __syncthreads();
  mm65(sm, sm + 4160, D);
}

// ---- 64x64 SPD Cholesky + explicit L^-1 (lower, zero upper) ----
__device__ void chol_inv(const float* S, float* Li, float* sm) {
  float (*M)[65] = (float (*)[65])sm;
  float (*T)[65] = (float (*)[65])(sm + 64 * 65);
  int tid = threadIdx.x;
  for (int e = tid; e < 4096; e += 256) {
    M[e >> 6][e & 63] = aload(S + e);
    T[e >> 6][e & 63] = 0.f;
  }
  __syncthreads();
  for (int j = 0; j < 64; ++j) {
    float pv = M[j][j];
    __syncthreads();
    float sc = rsqrtf(pv);
    if (tid < 64 - j) M[j + tid][j] *= sc;
    __syncthreads();
    int m = 63 - j, c2 = (m * (m + 1)) >> 1;
    for (int e = tid; e < c2; e += 256) {
      int rp = (int)((sqrtf(8.f * (float)e + 1.f) - 1.f) * 0.5f);
      while (((rp + 1) * (rp + 2)) >> 1 <= e) ++rp;
      while ((rp * (rp + 1)) >> 1 > e) --rp;
      int cp = e - ((rp * (rp + 1)) >> 1);
      int r = j + 1 + rp, c = j + 1 + cp;
      M[r][c] = fmaf(-M[r][j], M[c][j], M[r][c]);
    }
    __syncthreads();
  }
  if (tid < 64) {
    int c = tid;
    T[c][c] = 1.f / M[c][c];
    for (int r = c + 1; r < 64; ++r) {
      float s = 0.f;
      for (int t = c; t < r; ++t) s = fmaf(M[r][t], T[t][c], s);
      T[r][c] = -s / M[r][r];
    }
  }
  __syncthreads();
  for (int e = tid; e < 4096; e += 256) astore(Li + e, T[e >> 6][e & 63]);
}

// ---- partial projection: Opart[64][128] = P[:, 625-seg] @ f[625-seg, :] ----
__device__ void proj_seg(const float* P, const float* f, float* Opart, float* sm) {
  float* Pl = sm;  // [64][126]
  int tid = threadIdx.x;
  int rg = (tid >> 5) << 3;
  int cq = (tid & 31) << 2;
  float acc[8][4];
#pragma unroll
  for (int u = 0; u < 8; ++u)
#pragma unroll
    for (int v = 0; v < 4; ++v) acc[u][v] = 0.f;
  for (int t5 = 0; t5 < 5; ++t5) {
    int vb = t5 * 125;
    __syncthreads();
    for (int e = tid; e < 8000; e += 256) {
      int rr = e / 125, vv = e - rr * 125;
      Pl[rr * 126 + vv] = P[rr * NV + vb + vv];
    }
    __syncthreads();
    for (int vv = 0; vv < 125; ++vv) {
      float4 fv = *(const float4*)(f + (vb + vv) * 128 + cq);
#pragma unroll
      for (int u = 0; u < 8; ++u) {
        float pv = Pl[(rg + u) * 126 + vv];
        acc[u][0] = fmaf(pv, fv.x, acc[u][0]);
        acc[u][1] = fmaf(pv, fv.y, acc[u][1]);
        acc[u][2] = fmaf(pv, fv.z, acc[u][2]);
        acc[u][3] = fmaf(pv, fv.w, acc[u][3]);
      }
    }
  }
#pragma unroll
  for (int u = 0; u < 8; ++u)
#pragma unroll
    for (int v = 0; v < 4; ++v) astore(Opart + (rg + u) * 128 + cq + v, acc[u][v]);
}

// apply At: Y in pT (pT[col][row]) -> own element (row=lane, col=blk*4+wv); lct in regs
__device__ __forceinline__ float at_apply(const float (*pT)[68], const float* Rown,
                                          float* Tt, float* Pp, const float* lct,
                                          int lane, int wv) {
  float a0 = 0.f, a1 = 0.f, a2 = 0.f, a3 = 0.f;
  const float* R0 = Rown + wv * 256;
  for (int m = 0; m < 64; ++m) {
    float pv = pT[m][lane];
    a0 = fmaf(pv, R0[m], a0);
    a1 = fmaf(pv, R0[64 + m], a1);
    a2 = fmaf(pv, R0[128 + m], a2);
    a3 = fmaf(pv, R0[192 + m], a3);
  }
  Tt[0 + wv * 64 + lane] = a0;
  Tt[256 + wv * 64 + lane] = a1;
  Tt[512 + wv * 64 + lane] = a2;
  Tt[768 + wv * 64 + lane] = a3;
  __syncthreads();
  float p0 = 0.f, p1 = 0.f, p2 = 0.f, p3 = 0.f;
#pragma unroll
  for (int u = 0; u < 64; ++u) {
    float l = lct[u];
    int base = wv * 64 + u;
    p0 = fmaf(l, Tt[0 + base], p0);
    p1 = fmaf(l, Tt[256 + base], p1);
    p2 = fmaf(l, Tt[512 + base], p2);
    p3 = fmaf(l, Tt[768 + base], p3);
  }
  Pp[0 * 256 + wv * 64 + lane] = p0;
  Pp[1 * 256 + wv * 64 + lane] = p1;
  Pp[2 * 256 + wv * 64 + lane] = p2;
  Pp[3 * 256 + wv * 64 + lane] = p3;
  __syncthreads();
  return Pp[wv * 256 + lane] + Pp[wv * 256 + 64 + lane] +
         Pp[wv * 256 + 128 + lane] + Pp[wv * 256 + 192 + lane];
}

__global__ __launch_bounds__(256) void fused_kernel(
    const float* fx, const float* fy, const float* ex, const float* ey,
    const float* Px, const float* Py, const float* Mx, const float* My,
    float* W, float* out) {
  __shared__ float sm[10752];
  __shared__ float red[512];
  __shared__ float scal[8];
  int tid = threadIdx.x, blk = blockIdx.x;
  int lane = tid & 63, wv = tid >> 6;
  int* ctrl = (int*)(W + CTRL_O);
  int bt = 0;

  // ---- P0: sv (blk 0) + projection partials (all) ----
  if (blk == 0 && tid < 64) {
    float vx = ex[tid], vy = ey[tid];
    float m = fmaxf(vx, vy);
#pragma unroll
    for (int o = 32; o > 0; o >>= 1) m = fmaxf(m, __shfl_xor(m, o, 64));
    float g1 = sqrtf(vx / m), g2 = sqrtf(vy / m);   // GAMMA = 0.5
    float d1 = 1.f / fmaf(g1, g1, 1.f), d2 = 1.f / fmaf(g2, g2, 1.f);
    astore(W + SV_O + tid, g1 * d1);
    astore(W + SV_O + 64 + tid, d1);
    astore(W + SV_O + 128 + tid, g2 * d2);
    astore(W + SV_O + 192 + tid, d2);
  }
  {
    int mat = blk & 1, seg = blk >> 1;
    const float* P = mat ? Py : Px;
    const float* f = mat ? fy : fx;
    proj_seg(P + seg * 625, f + (size_t)seg * 625 * 128, W + PART_O + blk * 8192, sm);
  }
  gbar2(ctrl, blk, ++bt);

  // ---- P1: Ahat = Mx^T A fused-reduce (0-3), B0 reduce (4-7), H (8-15) ----
  if (blk < 4) {
    int c0 = blk * 32;
    for (int e = tid; e < 2048; e += 256) {
      int t = e >> 5, cl = e & 31;
      float s = 0.f;
#pragma unroll
      for (int p = 0; p < 8; ++p) s += aload(W + PART_O + (2 * p) * 8192 + t * 128 + c0 + cl);
      sm[t * 33 + cl] = s;
    }
    __syncthreads();
    for (int e = tid; e < 2048; e += 256) {
      int i = e >> 5, cl = e & 31;
      float acc = 0.f;
      for (int t = 0; t < 64; ++t) acc = fmaf(Mx[t * 64 + i], sm[t * 33 + cl], acc);
      astore(W + AH_O + i * 128 + c0 + cl, acc);
    }
  } else if (blk < 8) {
    int base = (blk - 4) * 2048;
    for (int e = tid; e < 2048; e += 256) {
      float s = 0.f;
#pragma unroll
      for (int p = 0; p < 8; ++p) s += aload(W + PART_O + (2 * p + 1) * 8192 + base + e);
      astore(W + B0_O + base + e, s);
    }
  } else {
    int base = (blk - 8) * 512;
    for (int e = tid; e < 512; e += 256) {
      int i = (base + e) >> 6, j = (base + e) & 63;
      float acc = 0.f;
      for (int t = 0; t < 64; ++t) acc = fmaf(My[t * 64 + i], My[t * 64 + j], acc);
      astore(W + H_O + base + e, acc);
    }
  }
  gbar2(ctrl, blk, ++bt);

  // ---- P2: E (0-3), Z2 (4-7), chol(H) (8), Q* (9-11) ----
  if (blk < 4) {
    for (int e = tid; e < 8192; e += 256) {
      int i = e >> 7, c = e & 127;
      sm[c * 65 + i] = aload(W + AH_O + e);     // AhT[c][i]
    }
    __syncthreads();
    int i0 = blk * 16;
    for (int e = tid; e < 1024; e += 256) {
      int i = i0 + (e >> 6), j = e & 63;
      float acc = 0.f;
#pragma unroll 8
      for (int c = 0; c < 128; ++c) acc = fmaf(sm[c * 65 + i], sm[c * 65 + j], acc);
      if (i == j) {
        float a = aload(W + SV_O + i), b = aload(W + SV_O + 64 + i);
        acc += LMB * (a * a + b * b);
      }
      astore(W + E_O + i * 64 + j, acc);
    }
  } else if (blk < 8) {
    int i0 = (blk - 4) * 16;
    for (int e = tid; e < 8192; e += 256) {
      int j = e >> 7, c = e & 127;
      sm[c * 65 + j] = aload(W + B0_O + e);     // B0T[c][j]
    }
    for (int e = tid; e < 2048; e += 256) {
      int il = e >> 7, c = e & 127;
      sm[8320 + c * 17 + il] = aload(W + AH_O + (i0 + il) * 128 + c);
    }
    __syncthreads();
    for (int e = tid; e < 1024; e += 256) {
      int il = e >> 6, j = e & 63;
      float acc = 0.f;
#pragma unroll 8
      for (int c = 0; c < 128; ++c) acc = fmaf(sm[8320 + c * 17 + il], sm[c * 65 + j], acc);
      astore(W + Z2_O + (i0 + il) * 64 + j, acc);
    }
  } else if (blk == 8) {
    chol_inv(W + H_O, W + LIH_O, sm);
  } else if (blk <= 11) {
    if (tid < 256) sm[tid] = aload(W + SV_O + tid);
    __syncthreads();
    int t = blk - 9;
    for (int e = tid; e < 4096; e += 256) {
      int k = e >> 6, b = e & 63;
      float h = aload(W + H_O + e), v;
      if (t == 0) v = h * (sm[128 + k] * sm[128 + b] + sm[192 + k] * sm[192 + b]);
      else if (t == 1) v = h * (sm[128 + k] + sm[128 + b]);
      else v = h * (sm[192 + k] + sm[192 + b]);
      astore(W + Q0_O + t * 4096 + e, v);
    }
  }
  gbar2(ctrl, blk, ++bt);

  // ---- P3: chol(E) (0), RH = Z2 H (1), U* = LiH Q* (2-4) ----
  if (blk == 0) chol_inv(W + E_O, W + LIE_O, sm);
  else if (blk == 1) mmNN_s(W + Z2_O, W + H_O, W + RH_O, sm);
  else if (blk <= 4) mmNN_s(W + LIH_O, W + Q0_O + (blk - 2) * 4096, W + U0_O + (blk - 2) * 4096, sm);
  gbar2(ctrl, blk, ++bt);

  // ---- P4: TB (0), QT* (1-3), E0 (4), Er/Ei (5-6) ----
  if (blk == 0) mmNN_s(W + LIE_O, W + RH_O, W + TB_O, sm);
  else if (blk <= 3) mmNT_s(W + U0_O + (blk - 1) * 4096, W + LIH_O, W + QT0_O + (blk - 1) * 4096, sm);
  else if (blk == 4) mmNT_s(W + LIE_O, W + LIE_O, W + E0_O, sm);
  else if (blk <= 6) {
    if (tid < 64) sm[8320 + tid] = aload(W + SV_O + ((blk == 5) ? tid : 64 + tid));
    __syncthreads();
    stageN(sm, W + LIE_O);
    for (int e = tid; e < 4096; e += 256) {
      int j = e >> 6, k = e & 63;
      sm[4160 + k * 65 + j] = aload(W + LIE_O + e) * sm[8320 + k];
    }
    __syncthreads();
    mm65(sm, sm + 4160, W + ((blk == 5) ? ER_O : EI_O));
  }
  gbar2(ctrl, blk, ++bt);

  // ---- P5: BT (0), RSTK pack (1-2), LCT pack (3-4) ----
  if (blk == 0) mmNT_s(W + TB_O, W + LIH_O, W + BT_O, sm);
  else if (blk <= 2) {
    for (int tt = 0; tt < 2; ++tt) {
      int t = (blk - 1) * 2 + tt;
      if (t == 0) {
        for (int e = tid; e < 4096; e += 256)
          astore(W + RSTK_O + e, ((e >> 6) == (e & 63)) ? 1.f : 0.f);
      } else {
        stageN(sm, W + QT0_O + (t - 1) * 4096);
        __syncthreads();
        for (int e = tid; e < 4096; e += 256) {
          int a = e >> 6, b = e & 63;
          astore(W + RSTK_O + t * 4096 + e, 0.5f * (sm[a * 65 + b] + sm[b * 65 + a]));
        }
        __syncthreads();
      }
    }
  } else if (blk <= 4) {
    for (int tt = 0; tt < 2; ++tt) {
      int t = (blk - 3) * 2 + tt;
      if (t == 0) {
        for (int e = tid; e < 4096; e += 256)
          astore(W + LCT_O + e, ((e >> 6) == (e & 63)) ? 1.f : 0.f);
      } else {
        float sgn = (t == 1) ? LMB : -LMB;
        stageN(sm, W + E0_O + (t - 1) * 4096);
        __syncthreads();
        for (int e = tid; e < 4096; e += 256) {
          int k = e >> 6, i = e & 63;
          astore(W + LCT_O + t * 4096 + e, sgn * 0.5f * (sm[k * 65 + i] + sm[i * 65 + k]));
        }
        __syncthreads();
      }
    }
  }
  gbar2(ctrl, blk, ++bt);

  // ---- P6: pipelined CG (all 16 blocks, 4 cols each) ----
  {
    float (*pT)[68] = (float (*)[68])sm;
    float* Rown = sm + 4352;
    float* Tt = Rown + 1024;
    float* Pp = Tt + 1024;
    float* wg = W + WG_O;
    float* RZp = W + RZP_O;
    float* PQp = W + PQP_O;
    int j0 = blk * 4, jown = j0 + wv;
    float lct[64];
#pragma unroll
    for (int u = 0; u < 64; ++u)
      lct[u] = aload(W + LCT_O + (wv * 64 + u) * 64 + lane);
    for (int e = tid; e < 1024; e += 256) {
      int t = e >> 8, jl = (e >> 6) & 3, m = e & 63;
      Rown[t * 256 + jl * 64 + m] = aload(W + RSTK_O + (t * 64 + j0 + jl) * 64 + m);
    }
    for (int u = 0; u < 16; ++u) {
      int g = u * 256 + tid;
      pT[g >> 6][g & 63] = aload(W + BT_O + (g & 63) * 64 + (g >> 6));
    }
    __syncthreads();
    float w_l = at_apply(pT, Rown, Tt, Pp, lct, lane, wv);
    float r_l = aload(W + BT_O + lane * 64 + jown);
    astore(&wg[jown * 64 + lane], w_l);
    red2(r_l * r_l, w_l * r_l, red, scal);
    if (tid == 0) { astore(&RZp[blk], scal[0]); astore(&PQp[blk], scal[1]); }
    gbar2(ctrl, blk, ++bt);

    float p_l = 0.f, q_l = 0.f, z_l = 0.f, x_l = 0.f;
    float gprev = 1.f, aprev = 1.f, g0 = 0.f;
    for (int j = 0; j < MAXIT; ++j) {
      if (tid < 32) {
        const float* src = (tid < 16) ? (RZp + j * 16) : (PQp + j * 16);
        float s = aload(src + (tid & 15));
        s += __shfl_xor(s, 1, 64);
        s += __shfl_xor(s, 2, 64);
        s += __shfl_xor(s, 4, 64);
        s += __shfl_xor(s, 8, 64);
        if ((tid & 15) == 0) scal[tid >> 4] = s;
      }
      __syncthreads();
      float gj = scal[0], dj = scal[1];
      if (j == 0) g0 = gj;
      if (j > 0 && gj < TOL * g0) break;
      float bj = (j == 0) ? 0.f : gj / gprev;
      float aj = (j == 0) ? gj / dj : gj / (dj - bj * gj / aprev);
      for (int u = 0; u < 16; ++u) {
        int g = u * 256 + tid;
        pT[g >> 6][g & 63] = aload(&wg[g]);
      }
      __syncthreads();
      float n_l = at_apply(pT, Rown, Tt, Pp, lct, lane, wv);
      z_l = fmaf(bj, z_l, n_l);
      q_l = fmaf(bj, q_l, w_l);
      p_l = fmaf(bj, p_l, r_l);
      x_l = fmaf(aj, p_l, x_l);
      r_l = fmaf(-aj, q_l, r_l);
      w_l = fmaf(-aj, z_l, w_l);
      astore(&wg[jown * 64 + lane], w_l);
      red2(r_l * r_l, w_l * r_l, red, scal + 2);
      if (tid == 0) {
        astore(&RZp[(j + 1) * 16 + blk], scal[2]);
        astore(&PQp[(j + 1) * 16 + blk], scal[3]);
      }
      gprev = gj; aprev = aj;
      gbar2(ctrl, blk, ++bt);
    }
    astore(&W[XG_O + jown * 64 + lane], x_l);   // Y col-major
  }
  gbar2(ctrl, blk, ++bt);

  // ---- P7: finish (block 0): out = (Mx LiE^T Y LiH)^T ----
  if (blk == 0) {
    float* Ys = sm;           // [64][65]: Ys[j][i] = Y[i][j]
    float* Ms2 = sm + 4160;   // staging
    float* V1 = sm + 8320 - 4160 + 8320;  // use sm+8320? need 3 regions
    // regions: Ys @0, Ms2 @4160, V1 @8320 (sm has 10752 -> V1 needs 4160: 8320+4160=12480 > 10752!)
    // instead reuse: V1 overwrites... compute V1 into separate quarter not possible; do in red? Use smaller pad for V1.
    // V1 unpadded [64][64] = 4096: 8320+4096 = 12416 still too big. Use Pp-style: V1 in [64][34]x2 passes.
    // Simplest: V1 unpadded at 6400..10496 (inside sm) after Ms2 freed? Ms2 needed during V1 compute.
    // Final layout: Ys@0 (4160), Ms2@4160 (4160), V1@8320 (2432 max) -> do V1 in two half passes.
    for (int e = tid; e < 4096; e += 256) Ys[(e >> 6) * 65 + (e & 63)] = aload(W + XG_O + e);
    for (int e = tid; e < 4096; e += 256) Ms2[(e >> 6) * 65 + (e & 63)] = aload(W + LIE_O + e);
    __syncthreads();
    // V1 = LiE^T Y, write to global scratch (reuse WG region) to avoid LDS overflow
    for (int e = tid; e < 4096; e += 256) {
      int t = e >> 6, b = e & 63;
      float acc = 0.f;
#pragma unroll 8
      for (int a = 0; a < 64; ++a) acc = fmaf(Ms2[a * 65 + t], Ys[b * 65 + a], acc);
      W[WG_O + t * 64 + b] = acc;   // block-0 private now; plain ok (same block reads)
    }
    __syncthreads();
    // stage V1 into Ys region (Ys no longer needed), LiH into Ms2
    for (int e = tid; e < 4096; e += 256) Ys[(e >> 6) * 65 + (e & 63)] = W[WG_O + e];
    for (int e = tid; e < 4096; e += 256) Ms2[(e >> 6) * 65 + (e & 63)] = aload(W + LIH_O + e);
    __syncthreads();
    // WH = V1 LiH -> store into W[WG_O] again
    for (int e = tid; e < 4096; e += 256) {
      int t = e >> 6, c = e & 63;
      float acc = 0.f;
#pragma unroll 8
      for (int b = 0; b < 64; ++b) acc = fmaf(Ys[t * 65 + b], Ms2[b * 65 + c], acc);
      W[WG_O + t * 64 + c] = acc;
    }
    __syncthreads();
    // stage WH into Ys, MxT into Ms2
    for (int e = tid; e < 4096; e += 256) Ys[(e >> 6) * 65 + (e & 63)] = W[WG_O + e];
    for (int e = tid; e < 4096; e += 256) Ms2[(e & 63) * 65 + (e >> 6)] = Mx[e]; // MxT[t][c]
    __syncthreads();
    for (int e = tid; e < 4096; e += 256) {
      int r = e >> 6, c = e & 63;
      float acc = 0.f;
#pragma unroll 8
      for (int t = 0; t < 64; ++t) acc = fmaf(Ms2[t * 65 + c], Ys[t * 65 + r], acc);
      out[e] = acc;
    }
  }
}

extern "C" void kernel_launch(void* const* d_in, const int* in_sizes, int n_in,
                              void* d_out, int out_size, void* d_ws, size_t ws_size,
                              hipStream_t stream) {
  const float* fx = (const float*)d_in[0];
  const float* fy = (const float*)d_in[1];
  const float* ex = (const float*)d_in[2];
  const float* ey = (const float*)d_in[3];
  const float* Px = (const float*)d_in[4];
  const float* Py = (const float*)d_in[5];
  const float* Mx = (const float*)d_in[6];
  const float* My = (const float*)d_in[7];
  float* out = (float*)d_out;
  float* W = (float*)d_ws;

  if (ws_size < (size_t)WS_NEED * sizeof(float)) {
    hipMemsetAsync(d_out, 0, (size_t)out_size * sizeof(float), stream);
    return;
  }

  init_kernel<<<4, 256, 0, stream>>>((int*)(W + CTRL_O));
  fused_kernel<<<NBLK, 256, 0, stream>>>(fx, fy, ex, ey, Px, Py, Mx, My, W, out);
}